// Round 5
// baseline (138.701 us; speedup 1.0000x reference)
//
#include <hip/hip_runtime.h>
#include <hip/hip_bf16.h>

#define N_ROWS 4096
#define TWO_N 8192
#define DIM 512
#define BK 32
#define INV_T 14.285714285714286f          // 1/0.07
#define LOG2E 1.4426950408889634f
#define C_LOG2E 20.60992915555662f          // (1/0.07)*log2(e)
#define INV_SQRT_T 3.7796447300922722f      // 1/sqrt(0.07)

typedef __bf16 bf16x8 __attribute__((ext_vector_type(8)));
typedef float f32x4 __attribute__((ext_vector_type(4)));

#define ASYNC_COPY16(gp, lp)                                                     \
  __builtin_amdgcn_global_load_lds((const __attribute__((address_space(1))) void*)(gp), \
                                   (__attribute__((address_space(3))) void*)(lp), 16, 0, 0)

// Fused: row norms, bf16 store of zhat/sqrt(T), positives in fp32,
// plus zeroing of rowsum (8192 floats).
__global__ void k_prep(const float* __restrict__ z1, const float* __restrict__ z2,
                       __hip_bfloat16* __restrict__ zn, float* __restrict__ posbuf,
                       float* __restrict__ rowsum) {
  __shared__ float red[12];
  const int r = blockIdx.x, t = threadIdx.x;
  if (r < 32) rowsum[r * 256 + t] = 0.f;           // 32*256 = 8192
  const float* p1 = z1 + (size_t)r * DIM;
  const float* p2 = z2 + (size_t)r * DIM;
  float a1 = p1[t], b1 = p1[t + 256];
  float a2 = p2[t], b2 = p2[t + 256];
  float s1 = a1 * a1 + b1 * b1;
  float s2 = a2 * a2 + b2 * b2;
  float sd = a1 * a2 + b1 * b2;
#pragma unroll
  for (int off = 32; off > 0; off >>= 1) {
    s1 += __shfl_down(s1, off, 64);
    s2 += __shfl_down(s2, off, 64);
    sd += __shfl_down(sd, off, 64);
  }
  const int w = t >> 6;
  if ((t & 63) == 0) { red[w] = s1; red[4 + w] = s2; red[8 + w] = sd; }
  __syncthreads();
  s1 = red[0] + red[1] + red[2] + red[3];
  s2 = red[4] + red[5] + red[6] + red[7];
  sd = red[8] + red[9] + red[10] + red[11];
  float sc1 = INV_SQRT_T / fmaxf(sqrtf(s1), 1e-8f);
  float sc2 = INV_SQRT_T / fmaxf(sqrtf(s2), 1e-8f);
  zn[(size_t)r * DIM + t]                    = __float2bfloat16(a1 * sc1);
  zn[(size_t)r * DIM + t + 256]              = __float2bfloat16(b1 * sc1);
  zn[(size_t)(r + N_ROWS) * DIM + t]         = __float2bfloat16(a2 * sc2);
  zn[(size_t)(r + N_ROWS) * DIM + t + 256]   = __float2bfloat16(b2 * sc2);
  if (t == 0) posbuf[r] = sd * sc1 * sc2;   // = cos(z1_r,z2_r)/T
}

// Flash-LSE GEMM over UPPER-TRIANGLE tiles (sim symmetric).
// Occupancy-focused: launch_bounds(256,4) -> 4 blocks/CU min; XCD-contiguous
// block remap so each XCD's 260 tiles form a contiguous triangle chunk.
__global__ __launch_bounds__(256, 4) void k_lse(const __hip_bfloat16* __restrict__ Zn,
                                                float* __restrict__ rowsum) {
  __shared__ char smem[32768] __attribute__((aligned(16)));
  const int tid  = threadIdx.x;
  const int wave = tid >> 6;
  const int lane = tid & 63;
  const int cl   = lane & 15;
  const int q    = lane >> 4;

  // XCD-aware remap: blockIdx%8 = XCD (round-robin dispatch); give each XCD a
  // contiguous chunk of 260 logical tiles for L2 locality.
  const int b = (blockIdx.x & 7) * 260 + (blockIdx.x >> 3);

  // linear b -> (rt, ct) with rt <= ct over 64x64 tile grid
  int rt = (int)((129.0f - sqrtf(16641.0f - 8.0f * (float)b)) * 0.5f);
  if (rt > 63) rt = 63;
  if (rt < 0) rt = 0;
  while (rt > 0 && 64 * rt - rt * (rt - 1) / 2 > b) rt--;
  while (64 * (rt + 1) - (rt + 1) * rt / 2 <= b) rt++;
  const int ct = rt + (b - (64 * rt - rt * (rt - 1) / 2));

  const int wr = (wave >> 1) * 64;   // wave's row offset in tile
  const int wc = (wave & 1) * 64;    // wave's col offset in tile

  // staging: thread owns slots g0=tid, g1=tid+256 of each 128x32 tile
  const int g0 = tid, g1 = tid + 256;
  const int r0 = g0 >> 2, k0 = (((g0 & 3) - ((g0 >> 4) & 3)) & 3) * 8;
  const int r1 = g1 >> 2, k1 = (((g1 & 3) - ((g1 >> 4) & 3)) & 3) * 8;
  const size_t aoff0 = (size_t)(rt * 128 + r0) * DIM + k0;
  const size_t aoff1 = (size_t)(rt * 128 + r1) * DIM + k1;
  const size_t boff0 = (size_t)(ct * 128 + r0) * DIM + k0;
  const size_t boff1 = (size_t)(ct * 128 + r1) * DIM + k1;

  f32x4 acc[4][4] = {};
  // fragment read k-granule: col = (q + (cl>>2)) & 3 (matches staging rotation)
  const int kx = ((q + (cl >> 2)) & 3) * 8;

#define STAGE(bufi, ko)                                                    \
  {                                                                        \
    char* dA = smem + (bufi) * 16384 + wave * 1024;                        \
    char* dB = smem + (bufi) * 16384 + 8192 + wave * 1024;                 \
    ASYNC_COPY16(Zn + aoff0 + (ko), dA);                                   \
    ASYNC_COPY16(Zn + aoff1 + (ko), dA + 4096);                            \
    ASYNC_COPY16(Zn + boff0 + (ko), dB);                                   \
    ASYNC_COPY16(Zn + boff1 + (ko), dB + 4096);                            \
  }

  STAGE(0, 0);
  for (int ks = 0; ks < DIM / BK; ks++) {
    const int cur = ks & 1;
    __syncthreads();                        // drains copy issued a full iter ago
    if (ks + 1 < DIM / BK) STAGE(1 - cur, (ks + 1) * BK);

    const char* sA = smem + cur * 16384;
    const char* sB = sA + 8192;
    bf16x8 af[4], bfr[4];
#pragma unroll
    for (int i = 0; i < 4; i++)
      af[i] = *reinterpret_cast<const bf16x8*>(sA + ((wr + i * 16 + cl) * BK + kx) * 2);
#pragma unroll
    for (int j = 0; j < 4; j++)
      bfr[j] = *reinterpret_cast<const bf16x8*>(sB + ((wc + j * 16 + cl) * BK + kx) * 2);
#pragma unroll
    for (int i = 0; i < 4; i++)
#pragma unroll
      for (int j = 0; j < 4; j++)
        acc[i][j] = __builtin_amdgcn_mfma_f32_16x16x32_bf16(af[i], bfr[j], acc[i][j], 0, 0, 0);
  }
#undef STAGE

  // Epilogue: e = exp(s - C) with diagonal masked.
  // C-layout: col = cl, row = q*4 + r (within 16x16 frag (i,j)).
  const bool diagw = (rt == ct) && (wr == wc);
  float psum[4][4];
#pragma unroll
  for (int i = 0; i < 4; i++)
#pragma unroll
    for (int r = 0; r < 4; r++) psum[i][r] = 0.f;
  float colp[4] = {0.f, 0.f, 0.f, 0.f};

#pragma unroll
  for (int i = 0; i < 4; i++)
#pragma unroll
    for (int j = 0; j < 4; j++)
#pragma unroll
      for (int r = 0; r < 4; r++) {
        float e = exp2f(fmaf(acc[i][j][r], LOG2E, -C_LOG2E));
        if (diagw && (i == j) && (cl == q * 4 + r)) e = 0.f;
        psum[i][r] += e;
        colp[j] += e;
      }

  // row sums -> rt rows (reduce across cols: cl lanes)
#pragma unroll
  for (int i = 0; i < 4; i++)
#pragma unroll
    for (int r = 0; r < 4; r++) {
      float v = psum[i][r];
      v += __shfl_xor(v, 1, 64);
      v += __shfl_xor(v, 2, 64);
      v += __shfl_xor(v, 4, 64);
      v += __shfl_xor(v, 8, 64);
      if (cl == 0) atomicAdd(&rowsum[rt * 128 + wr + i * 16 + q * 4 + r], v);
    }

  // col sums -> ct rows (reduce across rows: q lanes), only off-diagonal tiles
  if (rt != ct) {
#pragma unroll
    for (int j = 0; j < 4; j++) {
      float v = colp[j];
      v += __shfl_xor(v, 16, 64);
      v += __shfl_xor(v, 32, 64);
      if (q == 0) atomicAdd(&rowsum[ct * 128 + wc + j * 16 + cl], v);
    }
  }
}

// Single-kernel finalize: 1024 threads, 8 rows each.
__global__ void k_final(const float* __restrict__ rowsum, const float* __restrict__ posbuf,
                        float* __restrict__ out) {
  __shared__ float red[16];
  const int t = threadIdx.x;
  float s = 0.f;
#pragma unroll
  for (int r = t; r < TWO_N; r += 1024) s += logf(rowsum[r]);
#pragma unroll
  for (int r = t; r < N_ROWS; r += 1024) s -= 2.f * posbuf[r];
#pragma unroll
  for (int off = 32; off > 0; off >>= 1) s += __shfl_down(s, off, 64);
  if ((t & 63) == 0) red[t >> 6] = s;
  __syncthreads();
  if (t == 0) {
    float tot = 0.f;
#pragma unroll
    for (int w = 0; w < 16; w++) tot += red[w];
    out[0] = tot / (float)TWO_N + INV_T;
  }
}

extern "C" void kernel_launch(void* const* d_in, const int* in_sizes, int n_in,
                              void* d_out, int out_size, void* d_ws, size_t ws_size,
                              hipStream_t stream) {
  const float* z1 = (const float*)d_in[0];
  const float* z2 = (const float*)d_in[1];
  float* out = (float*)d_out;
  char* ws = (char*)d_ws;

  __hip_bfloat16* zn = (__hip_bfloat16*)ws;              // 8192*512*2 = 8388608 B
  float* rowsum = (float*)(ws + 8388608);                 // 8192*4 = 32768 B
  float* posbuf = (float*)(ws + 8421376);                 // 4096*4 = 16384 B

  k_prep<<<N_ROWS, 256, 0, stream>>>(z1, z2, zn, posbuf, rowsum);
  k_lse<<<2080, 256, 0, stream>>>(zn, rowsum);
  k_final<<<1, 1024, 0, stream>>>(rowsum, posbuf, out);
}